// Round 7
// baseline (505.929 us; speedup 1.0000x reference)
//
#include <hip/hip_runtime.h>
#include <hip/hip_bf16.h>
#include <math.h>

#define T_TOK 8192
#define D_DIM 2048
#define O_DIM 2048
#define E_NUM 8
#define BM 256
#define BN 256
#define BK 64

typedef __bf16 bf16_t;
typedef __bf16 bf16x8 __attribute__((ext_vector_type(8)));
typedef float fx4 __attribute__((ext_vector_type(4)));
typedef unsigned short us4 __attribute__((ext_vector_type(4)));

__device__ __forceinline__ unsigned short f2bf(float f) {
    unsigned int u = __builtin_bit_cast(unsigned int, f);
    u += 0x7FFFu + ((u >> 16) & 1u);           // round-to-nearest-even
    return (unsigned short)(u >> 16);
}

__device__ __forceinline__ void gll16(const void* g, void* l) {
    __builtin_amdgcn_global_load_lds(
        (const __attribute__((address_space(1))) void*)g,
        (__attribute__((address_space(3))) void*)l, 16, 0, 0);
}

// ---------------------------------------------------------------- prep
// Fused: blocks [0,2048) = gating (4 tokens/block), blocks [2048,6144) =
// expert_w fp32->bf16 conversion. Independent work, co-scheduled in one
// dispatch instead of serialized by the stream.
#define GATE_BLOCKS (T_TOK / 4)
#define CONV_BLOCKS 4096

__global__ __launch_bounds__(256) void prep_kernel(
    const float* __restrict__ x, const float* __restrict__ gw,
    const float* __restrict__ ew,
    bf16_t* __restrict__ xb, bf16_t* __restrict__ wb, int* __restrict__ cnt,
    int* __restrict__ tok_list, float* __restrict__ wgt_list) {
    if (blockIdx.x >= GATE_BLOCKS) {
        // ---- convert expert_w ----
        long n4 = (long)E_NUM * O_DIM * D_DIM / 4;
        long i = (long)(blockIdx.x - GATE_BLOCKS) * blockDim.x + threadIdx.x;
        long stride = (long)CONV_BLOCKS * blockDim.x;
        const float4* w4 = (const float4*)ew;
        us4* o4 = (us4*)wb;
        for (; i < n4; i += stride) {
            float4 v = w4[i];
            us4 o = { f2bf(v.x), f2bf(v.y), f2bf(v.z), f2bf(v.w) };
            o4[i] = o;
        }
        return;
    }
    // ---- gating: one wave per token ----
    int wid = threadIdx.x >> 6, lane = threadIdx.x & 63;
    int t = blockIdx.x * 4 + wid;

    const float4* xrow = (const float4*)(x + (size_t)t * D_DIM);
    float4 xv[8];
#pragma unroll
    for (int i = 0; i < 8; ++i) xv[i] = xrow[i * 64 + lane];

    float acc[E_NUM];
#pragma unroll
    for (int e = 0; e < E_NUM; ++e) {
        const float4* gr = (const float4*)(gw + (size_t)e * D_DIM);
        float s = 0.f;
#pragma unroll
        for (int i = 0; i < 8; ++i) {
            float4 g = gr[i * 64 + lane];
            s += xv[i].x * g.x + xv[i].y * g.y + xv[i].z * g.z + xv[i].w * g.w;
        }
        acc[e] = s;
    }
#pragma unroll
    for (int m = 1; m < 64; m <<= 1) {
#pragma unroll
        for (int e = 0; e < E_NUM; ++e) acc[e] += __shfl_xor(acc[e], m, 64);
    }

    us4* xbr = (us4*)(xb + (size_t)t * D_DIM);
#pragma unroll
    for (int i = 0; i < 8; ++i) {
        us4 o = { f2bf(xv[i].x), f2bf(xv[i].y), f2bf(xv[i].z), f2bf(xv[i].w) };
        xbr[i * 64 + lane] = o;
    }

    if (lane == 0) {
        int e0 = 0; float v0 = acc[0];
#pragma unroll
        for (int e = 1; e < E_NUM; ++e)
            if (acc[e] > v0) { v0 = acc[e]; e0 = e; }
        int e1 = -1; float v1 = -INFINITY;
#pragma unroll
        for (int e = 0; e < E_NUM; ++e)
            if (e != e0 && acc[e] > v1) { v1 = acc[e]; e1 = e; }
        float p1 = expf(v1 - v0);
        float denom = 1.f + p1;
        float w0 = 1.f / denom, w1 = p1 / denom;
        int s0 = atomicAdd(&cnt[e0], 1);
        tok_list[e0 * T_TOK + s0] = (t << 1);      // slot 0 -> out
        wgt_list[e0 * T_TOK + s0] = w0;
        int s1 = atomicAdd(&cnt[e1], 1);
        tok_list[e1 * T_TOK + s1] = (t << 1) | 1;  // slot 1 -> part
        wgt_list[e1 * T_TOK + s1] = w1;
    }
}

// ---------------------------------------------------------------- expert GEMM
// 8-phase-style 256x256 tile, BK=64, 8 waves (2M x 4N), K-half double-buffer.
// LDS map (bytes): dbuf d at d*65536; A-khalf h at +h*16384; B at +32768+h*16384.
// Within a half (256 rows x 32 k): row r at r*64, 16B slot s holds k-chunk
// kc = s ^ (r&3)  (XOR swizzle, applied on BOTH the pre-swizzled gll16 global
// source and the ds_read address — rule 21).
// Pipeline per tile t (dbuf d=t&1), 4 phases:
//   ph1: read Ah0 m0-3 + Bh0 (8 ds_read) | stage Ah1(t+1)->d^1 | lgkm0+bar | 16 MFMA
//   ph2: read Ah0 m4-7 (4)               | stage Bh1(t+1)->d^1 | vmcnt(8)+lgkm0+bar | 16 MFMA
//   ph3: read Ah1 m0-3 + Bh1 (8)         | stage Ah0(t+2)->d   | lgkm0+bar | 16 MFMA
//   ph4: read Ah1 m4-7 (4)               | stage Bh0(t+2)->d   | vmcnt(8)+lgkm0+bar | 16 MFMA
// kh0 regions die at ph2's barrier -> ph3/ph4 stages legally overwrite dbuf d.
// vmcnt(8) leaves the 4 newest half-tiles in flight (counted, never 0 mid-loop).
__global__ __launch_bounds__(512, 1) void expert_gemm(
    const bf16_t* __restrict__ xb, const bf16_t* __restrict__ wb,
    const float* __restrict__ eb, const int* __restrict__ cnt,
    const int* __restrict__ tok_list, const float* __restrict__ wgt_list,
    float* __restrict__ out, float* __restrict__ part) {
    int e = blockIdx.z;
    int count = cnt[e];
    int m0 = blockIdx.y * BM;
    if (m0 >= count) return;
    int n0 = blockIdx.x * BN;

    __shared__ alignas(16) unsigned char LDSB[131072];
    __shared__ int tok_s[BM];
    __shared__ float wgt_s[BM];

    int tid = threadIdx.x, wid = tid >> 6, L = tid & 63;
    int wr = wid >> 2, wc = wid & 3;          // 2 x 4 wave grid

    if (tid < BM) {
        int idx = m0 + tid;
        if (idx >= count) idx = count - 1;    // clamp; masked in epilogue
        tok_s[tid] = tok_list[e * T_TOK + idx];
        wgt_s[tid] = wgt_list[e * T_TOK + idx];
    }
    __syncthreads();

    // ---- staging geometry: wave w, call c covers rows 16*(w+8c)..+15 of the
    // 256-row half; lane L: row +=(L>>2), slot s=L&3 -> global kc = s^(r&3).
    int rA0 = wid * 16 + (L >> 2);            // call-0 row (0..127)
    int rA1 = rA0 + 128;                      // call-1 row
    int kcol = (((L & 3) ^ ((L >> 2) & 3)) * 8);  // pre-swizzled k-chunk (bf16)
    const bf16_t* gA0 = xb + (size_t)(tok_s[rA0] >> 1) * D_DIM + kcol;
    const bf16_t* gA1 = xb + (size_t)(tok_s[rA1] >> 1) * D_DIM + kcol;
    const bf16_t* wbase = wb + (size_t)e * O_DIM * D_DIM;
    const bf16_t* gB0 = wbase + (size_t)(n0 + rA0) * D_DIM + kcol;
    const bf16_t* gB1 = wbase + (size_t)(n0 + rA1) * D_DIM + kcol;
    unsigned sW = wid * 1024;                 // wave-uniform LDS offset, call0

#define STAGE_A(db, hh, koff) do {                                          \
        unsigned bb = (db) * 65536u + (hh) * 16384u + sW;                   \
        gll16(gA0 + (koff), LDSB + bb);                                     \
        gll16(gA1 + (koff), LDSB + bb + 8192); } while (0)
#define STAGE_B(db, hh, koff) do {                                          \
        unsigned bb = (db) * 65536u + 32768u + (hh) * 16384u + sW;          \
        gll16(gB0 + (koff), LDSB + bb);                                     \
        gll16(gB1 + (koff), LDSB + bb + 8192); } while (0)

    // ---- read geometry: lane L, frag row base m*16, reads row r=base+(L&15),
    // k-chunk (L>>4); swizzled slot = (L>>4)^(r&3), r&3 == L&3.
    unsigned xorp = ((unsigned)((L >> 4) ^ (L & 3))) * 16u;
    unsigned rowA = (unsigned)(wr * 128 + (L & 15)) * 64u;
    unsigned rowB = (unsigned)(wc * 64 + (L & 15)) * 64u;

#define LDA(base, MB)                                                       \
    _Pragma("unroll") for (int mm = 0; mm < 4; ++mm)                        \
        aq[mm] = *(const bf16x8*)(LDSB + (base) + rowA + (MB + mm) * 1024u + xorp);
#define LDB(base)                                                           \
    _Pragma("unroll") for (int nn = 0; nn < 4; ++nn)                        \
        bq[nn] = *(const bf16x8*)(LDSB + (base) + 32768u + rowB + nn * 1024u + xorp);
#define PH_MFMA(MB)                                                         \
    __builtin_amdgcn_s_setprio(1);                                          \
    _Pragma("unroll") for (int mm = 0; mm < 4; ++mm)                        \
        _Pragma("unroll") for (int nn = 0; nn < 4; ++nn)                    \
            acc[MB + mm][nn] = __builtin_amdgcn_mfma_f32_16x16x32_bf16(     \
                aq[mm], bq[nn], acc[MB + mm][nn], 0, 0, 0);                  \
    __builtin_amdgcn_s_setprio(0);
#define PHEND_LG  { asm volatile("s_waitcnt lgkmcnt(0)" ::: "memory");      \
                    __builtin_amdgcn_s_barrier();                           \
                    asm volatile("" ::: "memory"); }
#define PHEND_V8  { asm volatile("s_waitcnt vmcnt(8) lgkmcnt(0)" ::: "memory"); \
                    __builtin_amdgcn_s_barrier();                           \
                    asm volatile("" ::: "memory"); }
#define PHEND_V0  { asm volatile("s_waitcnt vmcnt(0) lgkmcnt(0)" ::: "memory"); \
                    __builtin_amdgcn_s_barrier();                           \
                    asm volatile("" ::: "memory"); }

    fx4 acc[8][4];
#pragma unroll
    for (int m = 0; m < 8; ++m)
#pragma unroll
        for (int n = 0; n < 4; ++n) acc[m][n] = (fx4)0.f;

    const int NT = D_DIM / BK;                // 32
    // prologue: tile0 all 4 halves -> dbuf0, tile1 kh0 -> dbuf1 (6 halves,
    // 12 gll16/wave). vmcnt(8): oldest 4 calls (Ah0(0),Bh0(0)) complete.
    STAGE_A(0, 0, 0);   STAGE_B(0, 0, 0);
    STAGE_A(0, 1, 32);  STAGE_B(0, 1, 32);
    STAGE_A(1, 0, 64);  STAGE_B(1, 0, 64);
    PHEND_V8;

    for (int t = 0; t < NT; ++t) {
        const int d = t & 1;
        const unsigned CA = (unsigned)d * 65536u;
        bf16x8 aq[4], bq[4];
        // ---- ph1: kh0, m0-3 (+B kh0) ----
        LDA(CA, 0); LDB(CA);
        if (t + 1 < NT) STAGE_A(d ^ 1, 1, (t + 1) * 64 + 32);
        PHEND_LG;
        PH_MFMA(0);
        // ---- ph2: kh0, m4-7 (B reused in regs) ----
        LDA(CA, 4);
        if (t + 1 < NT) { STAGE_B(d ^ 1, 1, (t + 1) * 64 + 32); PHEND_V8; }
        else            { PHEND_V0; }
        PH_MFMA(4);
        // ---- ph3: kh1, m0-3 (+B kh1) ----
        LDA(CA + 16384u, 0); LDB(CA + 16384u);
        if (t + 2 < NT) STAGE_A(d, 0, (t + 2) * 64);
        PHEND_LG;
        PH_MFMA(0);
        // ---- ph4: kh1, m4-7 ----
        LDA(CA + 16384u, 4);
        if (t + 2 < NT) { STAGE_B(d, 0, (t + 2) * 64); PHEND_V8; }
        else            { PHEND_V0; }
        PH_MFMA(4);
    }
#undef STAGE_A
#undef STAGE_B
#undef LDA
#undef LDB
#undef PH_MFMA
#undef PHEND_LG
#undef PHEND_V8
#undef PHEND_V0

    // epilogue: C/D layout col=L&15, row=(L>>4)*4+j. Plain stores.
    const float* ebias = eb + (size_t)e * O_DIM;
    int rr = L & 15, kq = L >> 4;
#pragma unroll
    for (int n = 0; n < 4; ++n) {
        int gcol = n0 + wc * 64 + n * 16 + rr;
        float bias = ebias[gcol];
#pragma unroll
        for (int m = 0; m < 8; ++m) {
            int rbase = wr * 128 + m * 16 + kq * 4;
#pragma unroll
            for (int j = 0; j < 4; ++j) {
                int r = rbase + j;
                if (m0 + r < count) {
                    int entry = tok_s[r];
                    float v = wgt_s[r] * (acc[m][n][j] + bias);
                    float* dst = (entry & 1) ? part : out;
                    dst[(size_t)(entry >> 1) * O_DIM + gcol] = v;
                }
            }
        }
    }
}

// ---------------------------------------------------------------- combine
__global__ __launch_bounds__(256) void combine_kernel(
    float* __restrict__ out, const float* __restrict__ part, long n4) {
    long i = (long)blockIdx.x * blockDim.x + threadIdx.x;
    long stride = (long)gridDim.x * blockDim.x;
    float4* o4 = (float4*)out;
    const float4* p4 = (const float4*)part;
    for (; i < n4; i += stride) {
        float4 a = o4[i], b = p4[i];
        a.x += b.x; a.y += b.y; a.z += b.z; a.w += b.w;
        o4[i] = a;
    }
}

// ---------------------------------------------------------------- launch
extern "C" void kernel_launch(void* const* d_in, const int* in_sizes, int n_in,
                              void* d_out, int out_size, void* d_ws, size_t ws_size,
                              hipStream_t stream) {
    const float* x        = (const float*)d_in[0];
    const float* gate_w   = (const float*)d_in[1];
    const float* expert_w = (const float*)d_in[2];
    const float* expert_b = (const float*)d_in[3];
    float* out = (float*)d_out;

    char* ws = (char*)d_ws;
    size_t off = 0;
    bf16_t* wb = (bf16_t*)(ws + off);      off += (size_t)E_NUM * O_DIM * D_DIM * 2;
    bf16_t* xb = (bf16_t*)(ws + off);      off += (size_t)T_TOK * D_DIM * 2;
    float*  part = (float*)(ws + off);     off += (size_t)T_TOK * O_DIM * 4;
    int*    tok_list = (int*)(ws + off);   off += (size_t)E_NUM * T_TOK * 4;
    float*  wgt_list = (float*)(ws + off); off += (size_t)E_NUM * T_TOK * 4;
    int*    cnt = (int*)(ws + off);        off += 64;

    hipMemsetAsync(cnt, 0, 64, stream);

    prep_kernel<<<GATE_BLOCKS + CONV_BLOCKS, 256, 0, stream>>>(
        x, gate_w, expert_w, xb, wb, cnt, tok_list, wgt_list);
    dim3 grid(O_DIM / BN, T_TOK / BM, E_NUM);
    expert_gemm<<<grid, 512, 0, stream>>>(
        xb, wb, expert_b, cnt, tok_list, wgt_list, out, part);
    combine_kernel<<<2048, 256, 0, stream>>>(
        out, part, (long)T_TOK * O_DIM / 4);
}

// Round 8
// 349.729 us; speedup vs baseline: 1.4466x; 1.4466x over previous
//
#include <hip/hip_runtime.h>
#include <hip/hip_bf16.h>
#include <math.h>

#define T_TOK 8192
#define D_DIM 2048
#define O_DIM 2048
#define E_NUM 8
#define BM 256
#define BN 256
#define BK 64

typedef __bf16 bf16_t;
typedef __bf16 bf16x8 __attribute__((ext_vector_type(8)));
typedef float fx4 __attribute__((ext_vector_type(4)));
typedef unsigned short us4 __attribute__((ext_vector_type(4)));

__device__ __forceinline__ unsigned short f2bf(float f) {
    unsigned int u = __builtin_bit_cast(unsigned int, f);
    u += 0x7FFFu + ((u >> 16) & 1u);           // round-to-nearest-even
    return (unsigned short)(u >> 16);
}

__device__ __forceinline__ void gll16(const void* g, void* l) {
    __builtin_amdgcn_global_load_lds(
        (const __attribute__((address_space(1))) void*)g,
        (__attribute__((address_space(3))) void*)l, 16, 0, 0);
}

// ---------------------------------------------------------------- convert W
// 4096 blocks x 256 thr, 8 INDEPENDENT float4 loads per thread (MLP), no
// grid-stride loop-carried deps. 8*2048*2048/4 = 8.39M float4 = 4096*2048.
__global__ __launch_bounds__(256) void convert_w_kernel(
    const float* __restrict__ w, bf16_t* __restrict__ wb) {
    long base = (long)blockIdx.x * 2048 + threadIdx.x;
    const float4* w4 = (const float4*)w;
    us4* o4 = (us4*)wb;
    float4 v[8];
#pragma unroll
    for (int k = 0; k < 8; ++k) v[k] = w4[base + k * 256];
#pragma unroll
    for (int k = 0; k < 8; ++k) {
        us4 o = { f2bf(v[k].x), f2bf(v[k].y), f2bf(v[k].z), f2bf(v[k].w) };
        o4[base + k * 256] = o;
    }
}

// ---------------------------------------------------------------- gating
// one wave per token. cnt is padded: counter for expert e at cnt[e*16]
// (one 64B line each) so the 16384 list-push atomics don't serialize on a
// single L2 line.
__global__ __launch_bounds__(256) void gate_kernel(
    const float* __restrict__ x, const float* __restrict__ gw,
    bf16_t* __restrict__ xb, int* __restrict__ cnt,
    int* __restrict__ tok_list, float* __restrict__ wgt_list) {
    int wid = threadIdx.x >> 6, lane = threadIdx.x & 63;
    int t = blockIdx.x * 4 + wid;

    const float4* xrow = (const float4*)(x + (size_t)t * D_DIM);
    float4 xv[8];
#pragma unroll
    for (int i = 0; i < 8; ++i) xv[i] = xrow[i * 64 + lane];

    float acc[E_NUM];
#pragma unroll
    for (int e = 0; e < E_NUM; ++e) {
        const float4* gr = (const float4*)(gw + (size_t)e * D_DIM);
        float s = 0.f;
#pragma unroll
        for (int i = 0; i < 8; ++i) {
            float4 g = gr[i * 64 + lane];
            s += xv[i].x * g.x + xv[i].y * g.y + xv[i].z * g.z + xv[i].w * g.w;
        }
        acc[e] = s;
    }
#pragma unroll
    for (int m = 1; m < 64; m <<= 1) {
#pragma unroll
        for (int e = 0; e < E_NUM; ++e) acc[e] += __shfl_xor(acc[e], m, 64);
    }

    us4* xbr = (us4*)(xb + (size_t)t * D_DIM);
#pragma unroll
    for (int i = 0; i < 8; ++i) {
        us4 o = { f2bf(xv[i].x), f2bf(xv[i].y), f2bf(xv[i].z), f2bf(xv[i].w) };
        xbr[i * 64 + lane] = o;
    }

    if (lane == 0) {
        int e0 = 0; float v0 = acc[0];
#pragma unroll
        for (int e = 1; e < E_NUM; ++e)
            if (acc[e] > v0) { v0 = acc[e]; e0 = e; }
        int e1 = -1; float v1 = -INFINITY;
#pragma unroll
        for (int e = 0; e < E_NUM; ++e)
            if (e != e0 && acc[e] > v1) { v1 = acc[e]; e1 = e; }
        float p1 = expf(v1 - v0);
        float denom = 1.f + p1;
        float w0 = 1.f / denom, w1 = p1 / denom;
        int s0 = atomicAdd(&cnt[e0 * 16], 1);
        tok_list[e0 * T_TOK + s0] = (t << 1);      // slot 0 -> out
        wgt_list[e0 * T_TOK + s0] = w0;
        int s1 = atomicAdd(&cnt[e1 * 16], 1);
        tok_list[e1 * T_TOK + s1] = (t << 1) | 1;  // slot 1 -> part
        wgt_list[e1 * T_TOK + s1] = w1;
    }
}

// ---------------------------------------------------------------- expert GEMM
// 8-phase-style 256x256 tile, BK=64, 8 waves (2M x 4N), K-half double-buffer.
// LDS map (bytes): dbuf d at d*65536; A-khalf h at +h*16384; B at +32768+h*16384.
// Within a half (256 rows x 32 k): row r at r*64; 16B slot s holds k-chunk
// kc = s ^ ((r>>2)&3).  [Round-7 used s ^ (r&3) — self-consistent but
// bank-ineffective: rows r,r+4,r+8,r+12 share r&3, leaving a 4-way conflict
// (1.3e7 counted). Row stride is 16 banks, so the colliding set differs in
// bits 3:2 — XOR those: rows {0,4,8,12} now hit 4 distinct granules, 2
// lanes/granule = free.]  Applied on BOTH sides (rule 21): pre-swizzled
// gll16 global source + swizzled ds_read address.
// Pipeline per tile t (dbuf d=t&1), 4 phases:
//   ph1: read Ah0 m0-3 + Bh0 (8 ds_read) | stage Ah1(t+1)->d^1 | lgkm0+bar | 16 MFMA
//   ph2: read Ah0 m4-7 (4)               | stage Bh1(t+1)->d^1 | vmcnt(8)+lgkm0+bar | 16 MFMA
//   ph3: read Ah1 m0-3 + Bh1 (8)         | stage Ah0(t+2)->d   | lgkm0+bar | 16 MFMA
//   ph4: read Ah1 m4-7 (4)               | stage Bh0(t+2)->d   | vmcnt(8)+lgkm0+bar | 16 MFMA
// kh0 regions die at ph2's barrier -> ph3/ph4 stages legally overwrite dbuf d.
// vmcnt(8) leaves the 4 newest half-tile calls in flight (counted, never 0).
__global__ __launch_bounds__(512, 1) void expert_gemm(
    const bf16_t* __restrict__ xb, const bf16_t* __restrict__ wb,
    const float* __restrict__ eb, const int* __restrict__ cnt,
    const int* __restrict__ tok_list, const float* __restrict__ wgt_list,
    float* __restrict__ out, float* __restrict__ part) {
    int e = blockIdx.z;
    int count = cnt[e * 16];
    int m0 = blockIdx.y * BM;
    if (m0 >= count) return;
    int n0 = blockIdx.x * BN;

    __shared__ alignas(16) unsigned char LDSB[131072];
    __shared__ int tok_s[BM];
    __shared__ float wgt_s[BM];

    int tid = threadIdx.x, wid = tid >> 6, L = tid & 63;
    int wr = wid >> 2, wc = wid & 3;          // 2 x 4 wave grid

    if (tid < BM) {
        int idx = m0 + tid;
        if (idx >= count) idx = count - 1;    // clamp; masked in epilogue
        tok_s[tid] = tok_list[e * T_TOK + idx];
        wgt_s[tid] = wgt_list[e * T_TOK + idx];
    }
    __syncthreads();

    // ---- staging geometry: wave w, call c covers rows 16*(w+8c)..+15 of the
    // 256-row half; lane L: row z=L>>2 within chunk, slot s=L&3 ->
    // global k-chunk kc = s ^ ((r>>2)&3) = (L&3) ^ (L>>4)  [chunk base
    // multiple of 16 -> (r>>2)&3 = (z>>2)&3 = (L>>4)&3; +128 rows: no change]
    int rA0 = wid * 16 + (L >> 2);            // call-0 row (0..127)
    int rA1 = rA0 + 128;                      // call-1 row
    int kcol = ((L & 3) ^ (L >> 4)) * 8;      // pre-swizzled k-chunk (bf16 elems)
    const bf16_t* gA0 = xb + (size_t)(tok_s[rA0] >> 1) * D_DIM + kcol;
    const bf16_t* gA1 = xb + (size_t)(tok_s[rA1] >> 1) * D_DIM + kcol;
    const bf16_t* wbase = wb + (size_t)e * O_DIM * D_DIM;
    const bf16_t* gB0 = wbase + (size_t)(n0 + rA0) * D_DIM + kcol;
    const bf16_t* gB1 = wbase + (size_t)(n0 + rA1) * D_DIM + kcol;
    unsigned sW = wid * 1024;                 // wave-uniform LDS offset, call0

#define STAGE_A(db, hh, koff) do {                                          \
        unsigned bb = (db) * 65536u + (hh) * 16384u + sW;                   \
        gll16(gA0 + (koff), LDSB + bb);                                     \
        gll16(gA1 + (koff), LDSB + bb + 8192); } while (0)
#define STAGE_B(db, hh, koff) do {                                          \
        unsigned bb = (db) * 65536u + 32768u + (hh) * 16384u + sW;          \
        gll16(gB0 + (koff), LDSB + bb);                                     \
        gll16(gB1 + (koff), LDSB + bb + 8192); } while (0)

    // ---- read geometry: lane L wants row r=base+(L&15), k-chunk q=L>>4 ->
    // slot = q ^ ((r>>2)&3) = (L>>4) ^ ((L>>2)&3)   [base multiple of 16]
    unsigned xorp = ((unsigned)((L >> 4) ^ ((L >> 2) & 3))) * 16u;
    unsigned rowA = (unsigned)(wr * 128 + (L & 15)) * 64u;
    unsigned rowB = (unsigned)(wc * 64 + (L & 15)) * 64u;

#define LDA(base, MB)                                                       \
    _Pragma("unroll") for (int mm = 0; mm < 4; ++mm)                        \
        aq[mm] = *(const bf16x8*)(LDSB + (base) + rowA + (MB + mm) * 1024u + xorp);
#define LDB(base)                                                           \
    _Pragma("unroll") for (int nn = 0; nn < 4; ++nn)                        \
        bq[nn] = *(const bf16x8*)(LDSB + (base) + 32768u + rowB + nn * 1024u + xorp);
#define PH_MFMA(MB)                                                         \
    __builtin_amdgcn_s_setprio(1);                                          \
    _Pragma("unroll") for (int mm = 0; mm < 4; ++mm)                        \
        _Pragma("unroll") for (int nn = 0; nn < 4; ++nn)                    \
            acc[MB + mm][nn] = __builtin_amdgcn_mfma_f32_16x16x32_bf16(     \
                aq[mm], bq[nn], acc[MB + mm][nn], 0, 0, 0);                  \
    __builtin_amdgcn_s_setprio(0);
#define PHEND_LG  { asm volatile("s_waitcnt lgkmcnt(0)" ::: "memory");      \
                    __builtin_amdgcn_s_barrier();                           \
                    asm volatile("" ::: "memory"); }
#define PHEND_V8  { asm volatile("s_waitcnt vmcnt(8) lgkmcnt(0)" ::: "memory"); \
                    __builtin_amdgcn_s_barrier();                           \
                    asm volatile("" ::: "memory"); }
#define PHEND_V0  { asm volatile("s_waitcnt vmcnt(0) lgkmcnt(0)" ::: "memory"); \
                    __builtin_amdgcn_s_barrier();                           \
                    asm volatile("" ::: "memory"); }

    fx4 acc[8][4];
#pragma unroll
    for (int m = 0; m < 8; ++m)
#pragma unroll
        for (int n = 0; n < 4; ++n) acc[m][n] = (fx4)0.f;

    const int NT = D_DIM / BK;                // 32
    // prologue: tile0 all 4 halves -> dbuf0, tile1 kh0 -> dbuf1 (6 halves,
    // 12 gll16/wave). vmcnt(8): oldest 4 calls (Ah0(0),Bh0(0)) complete.
    STAGE_A(0, 0, 0);   STAGE_B(0, 0, 0);
    STAGE_A(0, 1, 32);  STAGE_B(0, 1, 32);
    STAGE_A(1, 0, 64);  STAGE_B(1, 0, 64);
    PHEND_V8;

    for (int t = 0; t < NT; ++t) {
        const int d = t & 1;
        const unsigned CA = (unsigned)d * 65536u;
        bf16x8 aq[4], bq[4];
        // ---- ph1: kh0, m0-3 (+B kh0) ----
        LDA(CA, 0); LDB(CA);
        if (t + 1 < NT) STAGE_A(d ^ 1, 1, (t + 1) * 64 + 32);
        PHEND_LG;
        PH_MFMA(0);
        // ---- ph2: kh0, m4-7 (B reused in regs) ----
        LDA(CA, 4);
        if (t + 1 < NT) { STAGE_B(d ^ 1, 1, (t + 1) * 64 + 32); PHEND_V8; }
        else            { PHEND_V0; }
        PH_MFMA(4);
        // ---- ph3: kh1, m0-3 (+B kh1) ----
        LDA(CA + 16384u, 0); LDB(CA + 16384u);
        if (t + 2 < NT) STAGE_A(d, 0, (t + 2) * 64);
        PHEND_LG;
        PH_MFMA(0);
        // ---- ph4: kh1, m4-7 ----
        LDA(CA + 16384u, 4);
        if (t + 2 < NT) { STAGE_B(d, 0, (t + 2) * 64); PHEND_V8; }
        else            { PHEND_V0; }
        PH_MFMA(4);
    }
#undef STAGE_A
#undef STAGE_B
#undef LDA
#undef LDB
#undef PH_MFMA
#undef PHEND_LG
#undef PHEND_V8
#undef PHEND_V0

    // epilogue: C/D layout col=L&15, row=(L>>4)*4+j. Plain stores.
    const float* ebias = eb + (size_t)e * O_DIM;
    int rr = L & 15, kq = L >> 4;
#pragma unroll
    for (int n = 0; n < 4; ++n) {
        int gcol = n0 + wc * 64 + n * 16 + rr;
        float bias = ebias[gcol];
#pragma unroll
        for (int m = 0; m < 8; ++m) {
            int rbase = wr * 128 + m * 16 + kq * 4;
#pragma unroll
            for (int j = 0; j < 4; ++j) {
                int r = rbase + j;
                if (m0 + r < count) {
                    int entry = tok_s[r];
                    float v = wgt_s[r] * (acc[m][n][j] + bias);
                    float* dst = (entry & 1) ? part : out;
                    dst[(size_t)(entry >> 1) * O_DIM + gcol] = v;
                }
            }
        }
    }
}

// ---------------------------------------------------------------- combine
__global__ __launch_bounds__(256) void combine_kernel(
    float* __restrict__ out, const float* __restrict__ part, long n4) {
    long i = (long)blockIdx.x * blockDim.x + threadIdx.x;
    long stride = (long)gridDim.x * blockDim.x;
    float4* o4 = (float4*)out;
    const float4* p4 = (const float4*)part;
    for (; i < n4; i += stride) {
        float4 a = o4[i], b = p4[i];
        a.x += b.x; a.y += b.y; a.z += b.z; a.w += b.w;
        o4[i] = a;
    }
}

// ---------------------------------------------------------------- launch
extern "C" void kernel_launch(void* const* d_in, const int* in_sizes, int n_in,
                              void* d_out, int out_size, void* d_ws, size_t ws_size,
                              hipStream_t stream) {
    const float* x        = (const float*)d_in[0];
    const float* gate_w   = (const float*)d_in[1];
    const float* expert_w = (const float*)d_in[2];
    const float* expert_b = (const float*)d_in[3];
    float* out = (float*)d_out;

    char* ws = (char*)d_ws;
    size_t off = 0;
    bf16_t* wb = (bf16_t*)(ws + off);      off += (size_t)E_NUM * O_DIM * D_DIM * 2;
    bf16_t* xb = (bf16_t*)(ws + off);      off += (size_t)T_TOK * D_DIM * 2;
    float*  part = (float*)(ws + off);     off += (size_t)T_TOK * O_DIM * 4;
    int*    tok_list = (int*)(ws + off);   off += (size_t)E_NUM * T_TOK * 4;
    float*  wgt_list = (float*)(ws + off); off += (size_t)E_NUM * T_TOK * 4;
    int*    cnt = (int*)(ws + off);        off += 512;   // 8 counters, 64B apart

    hipMemsetAsync(cnt, 0, 512, stream);

    convert_w_kernel<<<4096, 256, 0, stream>>>(expert_w, wb);
    gate_kernel<<<T_TOK / 4, 256, 0, stream>>>(
        x, gate_w, xb, cnt, tok_list, wgt_list);
    dim3 grid(O_DIM / BN, T_TOK / BM, E_NUM);
    expert_gemm<<<grid, 512, 0, stream>>>(
        xb, wb, expert_b, cnt, tok_list, wgt_list, out, part);
    combine_kernel<<<2048, 256, 0, stream>>>(
        out, part, (long)T_TOK * O_DIM / 4);
}